// Round 6
// baseline (3071.297 us; speedup 1.0000x reference)
//
#include <hip/hip_runtime.h>
#include <math.h>

#define Bq 8
#define Hq 256
#define Wq 256
#define Cq 64
#define HID 8
#define PI_F 3.14159265358979323846f

typedef float f2 __attribute__((ext_vector_type(2)));

__device__ __forceinline__ f2 pkfma(f2 a, f2 b, f2 c) {
#if __has_builtin(__builtin_elementwise_fma)
    return __builtin_elementwise_fma(a, b, c);
#else
    f2 r; r.x = fmaf(a.x, b.x, c.x); r.y = fmaf(a.y, b.y, c.y); return r;
#endif
}
__device__ __forceinline__ f2 sp(float v) { f2 r; r.x = v; r.y = v; return r; }

// Sum v[hl&7] over the lane's OWN 32-lane half (two pixels per wave).
__device__ __forceinline__ float fold8h(float v0, float v1, float v2, float v3,
                                        float v4, float v5, float v6, float v7,
                                        int hl) {
    const bool b4 = (hl & 4) != 0;
    float k0 = b4 ? v4 : v0, g0 = b4 ? v0 : v4;
    float k1 = b4 ? v5 : v1, g1 = b4 ? v1 : v5;
    float k2 = b4 ? v6 : v2, g2 = b4 ? v2 : v6;
    float k3 = b4 ? v7 : v3, g3 = b4 ? v3 : v7;
    k0 += __shfl_xor(g0, 4, 64);
    k1 += __shfl_xor(g1, 4, 64);
    k2 += __shfl_xor(g2, 4, 64);
    k3 += __shfl_xor(g3, 4, 64);
    const bool b2 = (hl & 2) != 0;
    float m0 = b2 ? k2 : k0, n0 = b2 ? k0 : k2;
    float m1 = b2 ? k3 : k1, n1 = b2 ? k1 : k3;
    m0 += __shfl_xor(n0, 2, 64);
    m1 += __shfl_xor(n1, 2, 64);
    const bool b1_ = (hl & 1) != 0;
    float q = b1_ ? m1 : m0, r = b1_ ? m0 : m1;
    q += __shfl_xor(r, 1, 64);
    q += __shfl_xor(q, 8, 64);
    q += __shfl_xor(q, 16, 64);
    return q;
}

// Packed bilinear sample: lane covers channels (2hl, 2hl+1) of its half's
// pixel. Clipped-integer-corner weights, faithful to the reference.
__device__ __forceinline__ void bilin2(const char* __restrict__ xb, unsigned laneoff,
                                       float cy, float cx, f2& acc) {
    float fy0 = floorf(cy), fx0 = floorf(cx);
    int y0 = (int)fy0, x0 = (int)fx0;
    int y0i = min(max(y0, 0), Hq - 1);
    int y1i = min(max(y0 + 1, 0), Hq - 1);
    int x0i = min(max(x0, 0), Wq - 1);
    int x1i = min(max(x0 + 1, 0), Wq - 1);
    unsigned r0 = ((unsigned)y0i << 16) + laneoff;
    unsigned r1 = ((unsigned)y1i << 16) + laneoff;
    unsigned c0 = (unsigned)x0i << 8, c1 = (unsigned)x1i << 8;
    f2 Ia = *(const f2*)(xb + (r0 + c0));
    f2 Ib = *(const f2*)(xb + (r1 + c0));
    f2 Ic = *(const f2*)(xb + (r0 + c1));
    f2 Id = *(const f2*)(xb + (r1 + c1));
    float wy0 = (float)y1i - cy, wy1 = cy - (float)y0i;
    float wx0 = (float)x1i - cx, wx1 = cx - (float)x0i;
    acc = pkfma(sp(wx0 * wy0), Ia, acc);
    acc = pkfma(sp(wx0 * wy1), Ib, acc);
    acc = pkfma(sp(wx1 * wy0), Ic, acc);
    acc = pkfma(sp(wx1 * wy1), Id, acc);
}

// Repack w3 [9][64][8] -> ws[tap][hl][j] = {w3[tap][2hl][j], w3[tap][2hl+1][j]}
// and wr [128][8] -> pairs. 2816 f2 elements.
__global__ void repack_kernel(const float* __restrict__ w3,
                              const float* __restrict__ wr,
                              f2* __restrict__ ws) {
    int t = blockIdx.x * 256 + threadIdx.x;
    if (t < 2304) {
        int tap = t >> 8, rem = t & 255, hl = rem >> 3, j = rem & 7;
        f2 v; v.x = w3[((tap << 6) + (hl << 1)) * 8 + j];
        v.y = w3[((tap << 6) + (hl << 1) + 1) * 8 + j];
        ws[t] = v;
    } else if (t < 2560) {
        int rem = t - 2304, hl = rem >> 3, j = rem & 7;
        f2 v; v.x = wr[(hl << 1) * 8 + j];
        v.y = wr[((hl << 1) + 1) * 8 + j];
        ws[t] = v;
    } else if (t < 2816) {
        int rem = t - 2560, hl = rem >> 3, j = rem & 7;
        f2 v; v.x = wr[(64 + (hl << 1)) * 8 + j];
        v.y = wr[(64 + (hl << 1) + 1) * 8 + j];
        ws[t] = v;
    }
}

// Kernel A: conv3x3 -> h -> theta -> {cos, sin} per pixel into wsTheta.
__global__ __launch_bounds__(256, 8) void theta_kernel(
    const float* __restrict__ x,
    const float* __restrict__ b3, const float* __restrict__ w1,
    const float* __restrict__ b1, const f2* __restrict__ ws,
    f2* __restrict__ wsTheta) {
    const int lane = threadIdx.x & 63;
    const int hl = lane & 31;
    const int half = lane >> 5;
    const int w = __builtin_amdgcn_readfirstlane(blockIdx.x * 4 + (threadIdx.x >> 6));
    const int b   = w >> 15;
    const int yq  = (w >> 7) & 255;
    const int xq0 = (2 * w) & 255;
    const int xql = xq0 + half;
    const char* xb = (const char*)(x + ((size_t)b << 22));
    const unsigned laneoff = (unsigned)hl << 3;

    f2 a0 = sp(0.f), a1 = sp(0.f), a2 = sp(0.f), a3 = sp(0.f);
    f2 a4 = sp(0.f), a5 = sp(0.f), a6 = sp(0.f), a7 = sp(0.f);
#pragma unroll
    for (int dy = -1; dy <= 1; ++dy) {
#pragma unroll
        for (int dx = -1; dx <= 1; ++dx) {
            int yy = yq + dy;
            int xx = xql + dx;
            int yyc = min(max(yy, 0), Hq - 1);
            int xxc = min(max(xx, 0), Wq - 1);
            bool valid = ((unsigned)yy < (unsigned)Hq) && ((unsigned)xx < (unsigned)Wq);
            f2 xv = *(const f2*)(xb + (((unsigned)yyc << 16) + ((unsigned)xxc << 8) + laneoff));
            xv = valid ? xv : sp(0.f);
            const int tap = (dy + 1) * 3 + (dx + 1);
            const f2* wp = ws + (tap << 8) + (hl << 3);
            a0 = pkfma(xv, wp[0], a0);
            a1 = pkfma(xv, wp[1], a1);
            a2 = pkfma(xv, wp[2], a2);
            a3 = pkfma(xv, wp[3], a3);
            a4 = pkfma(xv, wp[4], a4);
            a5 = pkfma(xv, wp[5], a5);
            a6 = pkfma(xv, wp[6], a6);
            a7 = pkfma(xv, wp[7], a7);
        }
    }
    const int j = hl & 7;
    float hsum = fold8h(a0.x + a0.y, a1.x + a1.y, a2.x + a2.y, a3.x + a3.y,
                        a4.x + a4.y, a5.x + a5.y, a6.x + a6.y, a7.x + a7.y, hl);
    float h_l = fmaxf(hsum + b3[j], 0.f);

    float zp = h_l * w1[j];
    zp += __shfl_xor(zp, 1, 64);
    zp += __shfl_xor(zp, 2, 64);
    zp += __shfl_xor(zp, 4, 64);
    float z = zp + b1[0];
    float theta = PI_F * __builtin_amdgcn_rcpf(1.f + __expf(-z));
    f2 cs; cs.x = __cosf(theta); cs.y = __sinf(theta);
    if (hl == 0) wsTheta[2 * w + half] = cs;
}

// Kernel B: oriented pooling + gating + output.
__global__ __launch_bounds__(256, 8) void pool_kernel(
    const float* __restrict__ x,
    const float* __restrict__ br, const float* __restrict__ we,
    const float* __restrict__ be, const f2* __restrict__ ws,
    const f2* __restrict__ wsTheta,
    float* __restrict__ out) {
    const int lane = threadIdx.x & 63;
    const int hl = lane & 31;
    const int half = lane >> 5;
    const int w = __builtin_amdgcn_readfirstlane(blockIdx.x * 4 + (threadIdx.x >> 6));
    const int b   = w >> 15;
    const int yq  = (w >> 7) & 255;
    const int xq0 = (2 * w) & 255;
    const int xql = xq0 + half;
    const char* xb = (const char*)(x + ((size_t)b << 22));
    const unsigned laneoff = (unsigned)hl << 3;

    f2 cs = wsTheta[2 * w + half];
    const float ct = cs.x, st = cs.y;

    const float fy = (float)yq, fx = (float)xql;
    f2 at0 = sp(0.f), at1 = sp(0.f), an0 = sp(0.f), an1 = sp(0.f);
#pragma unroll
    for (int t = -4; t <= 4; ++t) {
        float tf = (float)t;
        bilin2(xb, laneoff, fmaf(tf, st, fy), fmaf(tf, ct, fx), (t & 1) ? at1 : at0);
        bilin2(xb, laneoff, fmaf(tf, ct, fy), fmaf(-tf, st, fx), (t & 1) ? an1 : an0);
    }
    f2 tan2; tan2.x = (at0.x + at1.x) * (1.f / 9.f); tan2.y = (at0.y + at1.y) * (1.f / 9.f);
    f2 nor2; nor2.x = (an0.x + an1.x) * (1.f / 9.f); nor2.y = (an0.y + an1.y) * (1.f / 9.f);

    // ---- r = relu(wr . [tan;nor] + br) ----
    const int j = hl & 7;
    const f2* wrp = ws + 2304 + (hl << 3);
    const f2* wrn = ws + 2560 + (hl << 3);
    f2 p0 = pkfma(tan2, wrp[0], sp(0.f)); p0 = pkfma(nor2, wrn[0], p0);
    f2 p1 = pkfma(tan2, wrp[1], sp(0.f)); p1 = pkfma(nor2, wrn[1], p1);
    f2 p2 = pkfma(tan2, wrp[2], sp(0.f)); p2 = pkfma(nor2, wrn[2], p2);
    f2 p3 = pkfma(tan2, wrp[3], sp(0.f)); p3 = pkfma(nor2, wrn[3], p3);
    f2 p4 = pkfma(tan2, wrp[4], sp(0.f)); p4 = pkfma(nor2, wrn[4], p4);
    f2 p5 = pkfma(tan2, wrp[5], sp(0.f)); p5 = pkfma(nor2, wrn[5], p5);
    f2 p6 = pkfma(tan2, wrp[6], sp(0.f)); p6 = pkfma(nor2, wrn[6], p6);
    f2 p7 = pkfma(tan2, wrp[7], sp(0.f)); p7 = pkfma(nor2, wrn[7], p7);
    float rsum = fold8h(p0.x + p0.y, p1.x + p1.y, p2.x + p2.y, p3.x + p3.y,
                        p4.x + p4.y, p5.x + p5.y, p6.x + p6.y, p7.x + p7.y, hl);
    float r_l = fmaxf(rsum + br[j], 0.f);   // lane holds r[j], j = hl&7

    // broadcast within half: slot m holds r[j ^ m]
    float rb0 = r_l;
    float rb1 = __shfl_xor(rb0, 1, 64);
    float rb2 = __shfl_xor(rb0, 2, 64);
    float rb3 = __shfl_xor(rb1, 2, 64);
    float rb4 = __shfl_xor(rb0, 4, 64);
    float rb5 = __shfl_xor(rb1, 4, 64);
    float rb6 = __shfl_xor(rb2, 4, 64);
    float rb7 = __shfl_xor(rb3, 4, 64);

    // ---- w = sigmoid(we . r + be), packed channel pairs ----
    const char* web = (const char*)we;
    unsigned voff = ((unsigned)j << 9) | laneoff;
    f2 zt2 = *(const f2*)((const char*)be + laneoff);
    f2 zn2 = *(const f2*)((const char*)be + 256 + laneoff);
#pragma unroll
    for (int m = 0; m < 8; ++m) {
        unsigned vm = voff ^ ((unsigned)m << 9);
        float rbm = (m == 0) ? rb0 : (m == 1) ? rb1 : (m == 2) ? rb2 : (m == 3) ? rb3
                  : (m == 4) ? rb4 : (m == 5) ? rb5 : (m == 6) ? rb6 : rb7;
        zt2 = pkfma(sp(rbm), *(const f2*)(web + vm), zt2);
        zn2 = pkfma(sp(rbm), *(const f2*)(web + vm + 256), zn2);
    }
    f2 wt2, wn2;
    wt2.x = __builtin_amdgcn_rcpf(1.f + __expf(-zt2.x));
    wt2.y = __builtin_amdgcn_rcpf(1.f + __expf(-zt2.y));
    wn2.x = __builtin_amdgcn_rcpf(1.f + __expf(-zn2.x));
    wn2.y = __builtin_amdgcn_rcpf(1.f + __expf(-zn2.y));

    f2 xc2 = *(const f2*)(xb + (((unsigned)yq << 16) + ((unsigned)xql << 8) + laneoff));
    f2 o; o.x = (wt2.x + wn2.x) * xc2.x; o.y = (wt2.y + wn2.y) * xc2.y;
    *(f2*)((char*)out + (((size_t)w) << 9) + ((unsigned)lane << 3)) = o;
}

extern "C" void kernel_launch(void* const* d_in, const int* in_sizes, int n_in,
                              void* d_out, int out_size, void* d_ws, size_t ws_size,
                              hipStream_t stream) {
    const float* x  = (const float*)d_in[0];
    const float* w3 = (const float*)d_in[1];
    const float* b3 = (const float*)d_in[2];
    const float* w1 = (const float*)d_in[3];
    const float* b1 = (const float*)d_in[4];
    const float* wr = (const float*)d_in[5];
    const float* br = (const float*)d_in[6];
    const float* we = (const float*)d_in[7];
    const float* be = (const float*)d_in[8];
    float* out = (float*)d_out;
    f2* ws = (f2*)d_ws;
    f2* wsTheta = ws + 4096;   // 512K f2 = 4 MB for per-pixel {cos, sin}

    repack_kernel<<<11, 256, 0, stream>>>(w3, wr, ws);

    const int total_waves = Bq * Hq * Wq / 2;   // one wave per pixel PAIR
    dim3 grid(total_waves / 4), block(256);
    theta_kernel<<<grid, block, 0, stream>>>(x, b3, w1, b1, ws, wsTheta);
    pool_kernel<<<grid, block, 0, stream>>>(x, br, we, be, ws, wsTheta, out);
}

// Round 7
// 1361.081 us; speedup vs baseline: 2.2565x; 2.2565x over previous
//
#include <hip/hip_runtime.h>
#include <math.h>

#define Bq 8
#define Hq 256
#define Wq 256
#define Cq 64
#define HID 8
#define PI_F 3.14159265358979323846f

typedef float f2 __attribute__((ext_vector_type(2)));

__device__ __forceinline__ f2 pkfma(f2 a, f2 b, f2 c) {
#if __has_builtin(__builtin_elementwise_fma)
    return __builtin_elementwise_fma(a, b, c);
#else
    f2 r; r.x = fmaf(a.x, b.x, c.x); r.y = fmaf(a.y, b.y, c.y); return r;
#endif
}
__device__ __forceinline__ f2 sp(float v) { f2 r; r.x = v; r.y = v; return r; }

// Sum v[hl&7] over the lane's OWN 32-lane half (two pixels per wave).
__device__ __forceinline__ float fold8h(float v0, float v1, float v2, float v3,
                                        float v4, float v5, float v6, float v7,
                                        int hl) {
    const bool b4 = (hl & 4) != 0;
    float k0 = b4 ? v4 : v0, g0 = b4 ? v0 : v4;
    float k1 = b4 ? v5 : v1, g1 = b4 ? v1 : v5;
    float k2 = b4 ? v6 : v2, g2 = b4 ? v2 : v6;
    float k3 = b4 ? v7 : v3, g3 = b4 ? v3 : v7;
    k0 += __shfl_xor(g0, 4, 64);
    k1 += __shfl_xor(g1, 4, 64);
    k2 += __shfl_xor(g2, 4, 64);
    k3 += __shfl_xor(g3, 4, 64);
    const bool b2 = (hl & 2) != 0;
    float m0 = b2 ? k2 : k0, n0 = b2 ? k0 : k2;
    float m1 = b2 ? k3 : k1, n1 = b2 ? k1 : k3;
    m0 += __shfl_xor(n0, 2, 64);
    m1 += __shfl_xor(n1, 2, 64);
    const bool b1_ = (hl & 1) != 0;
    float q = b1_ ? m1 : m0, r = b1_ ? m0 : m1;
    q += __shfl_xor(r, 1, 64);
    q += __shfl_xor(q, 8, 64);
    q += __shfl_xor(q, 16, 64);
    return q;
}

// Packed bilinear sample: lane covers channels (2hl, 2hl+1) of its half's
// pixel. Clipped-integer-corner weights, faithful to the reference.
__device__ __forceinline__ void bilin2(const char* __restrict__ xb, unsigned laneoff,
                                       float cy, float cx, f2& acc) {
    float fy0 = floorf(cy), fx0 = floorf(cx);
    int y0 = (int)fy0, x0 = (int)fx0;
    int y0i = min(max(y0, 0), Hq - 1);
    int y1i = min(max(y0 + 1, 0), Hq - 1);
    int x0i = min(max(x0, 0), Wq - 1);
    int x1i = min(max(x0 + 1, 0), Wq - 1);
    unsigned r0 = ((unsigned)y0i << 16) + laneoff;
    unsigned r1 = ((unsigned)y1i << 16) + laneoff;
    unsigned c0 = (unsigned)x0i << 8, c1 = (unsigned)x1i << 8;
    f2 Ia = *(const f2*)(xb + (r0 + c0));
    f2 Ib = *(const f2*)(xb + (r1 + c0));
    f2 Ic = *(const f2*)(xb + (r0 + c1));
    f2 Id = *(const f2*)(xb + (r1 + c1));
    float wy0 = (float)y1i - cy, wy1 = cy - (float)y0i;
    float wx0 = (float)x1i - cx, wx1 = cx - (float)x0i;
    acc = pkfma(sp(wx0 * wy0), Ia, acc);
    acc = pkfma(sp(wx0 * wy1), Ib, acc);
    acc = pkfma(sp(wx1 * wy0), Ic, acc);
    acc = pkfma(sp(wx1 * wy1), Id, acc);
}

// Repack w3 [9][64][8] -> ws[tap][hl][j] = {w3[tap][2hl][j], w3[tap][2hl+1][j]}
// and wr [128][8] -> pairs. 2816 f2 elements.
__global__ void repack_kernel(const float* __restrict__ w3,
                              const float* __restrict__ wr,
                              f2* __restrict__ ws) {
    int t = blockIdx.x * 256 + threadIdx.x;
    if (t < 2304) {
        int tap = t >> 8, rem = t & 255, hl = rem >> 3, j = rem & 7;
        f2 v; v.x = w3[((tap << 6) + (hl << 1)) * 8 + j];
        v.y = w3[((tap << 6) + (hl << 1) + 1) * 8 + j];
        ws[t] = v;
    } else if (t < 2560) {
        int rem = t - 2304, hl = rem >> 3, j = rem & 7;
        f2 v; v.x = wr[(hl << 1) * 8 + j];
        v.y = wr[((hl << 1) + 1) * 8 + j];
        ws[t] = v;
    } else if (t < 2816) {
        int rem = t - 2560, hl = rem >> 3, j = rem & 7;
        f2 v; v.x = wr[(64 + (hl << 1)) * 8 + j];
        v.y = wr[(64 + (hl << 1) + 1) * 8 + j];
        ws[t] = v;
    }
}

// Kernel A: conv3x3 -> h -> theta -> {cos, sin} per pixel into wsTheta.
// NOTE: no min-waves arg — __launch_bounds__(256, 8) forced a 32-VGPR
// allocation and catastrophic scratch spilling (round 6: 9 GB HBM traffic).
__global__ __launch_bounds__(256) void theta_kernel(
    const float* __restrict__ x,
    const float* __restrict__ b3, const float* __restrict__ w1,
    const float* __restrict__ b1, const f2* __restrict__ ws,
    f2* __restrict__ wsTheta) {
    const int lane = threadIdx.x & 63;
    const int hl = lane & 31;
    const int half = lane >> 5;
    const int w = __builtin_amdgcn_readfirstlane(blockIdx.x * 4 + (threadIdx.x >> 6));
    const int b   = w >> 15;
    const int yq  = (w >> 7) & 255;
    const int xq0 = (2 * w) & 255;
    const int xql = xq0 + half;
    const char* xb = (const char*)(x + ((size_t)b << 22));
    const unsigned laneoff = (unsigned)hl << 3;

    f2 a0 = sp(0.f), a1 = sp(0.f), a2 = sp(0.f), a3 = sp(0.f);
    f2 a4 = sp(0.f), a5 = sp(0.f), a6 = sp(0.f), a7 = sp(0.f);
#pragma unroll
    for (int dy = -1; dy <= 1; ++dy) {
#pragma unroll
        for (int dx = -1; dx <= 1; ++dx) {
            int yy = yq + dy;
            int xx = xql + dx;
            int yyc = min(max(yy, 0), Hq - 1);
            int xxc = min(max(xx, 0), Wq - 1);
            bool valid = ((unsigned)yy < (unsigned)Hq) && ((unsigned)xx < (unsigned)Wq);
            f2 xv = *(const f2*)(xb + (((unsigned)yyc << 16) + ((unsigned)xxc << 8) + laneoff));
            xv = valid ? xv : sp(0.f);
            const int tap = (dy + 1) * 3 + (dx + 1);
            const f2* wp = ws + (tap << 8) + (hl << 3);
            a0 = pkfma(xv, wp[0], a0);
            a1 = pkfma(xv, wp[1], a1);
            a2 = pkfma(xv, wp[2], a2);
            a3 = pkfma(xv, wp[3], a3);
            a4 = pkfma(xv, wp[4], a4);
            a5 = pkfma(xv, wp[5], a5);
            a6 = pkfma(xv, wp[6], a6);
            a7 = pkfma(xv, wp[7], a7);
        }
    }
    const int j = hl & 7;
    float hsum = fold8h(a0.x + a0.y, a1.x + a1.y, a2.x + a2.y, a3.x + a3.y,
                        a4.x + a4.y, a5.x + a5.y, a6.x + a6.y, a7.x + a7.y, hl);
    float h_l = fmaxf(hsum + b3[j], 0.f);

    float zp = h_l * w1[j];
    zp += __shfl_xor(zp, 1, 64);
    zp += __shfl_xor(zp, 2, 64);
    zp += __shfl_xor(zp, 4, 64);
    float z = zp + b1[0];
    float theta = PI_F * __builtin_amdgcn_rcpf(1.f + __expf(-z));
    f2 cs; cs.x = __cosf(theta); cs.y = __sinf(theta);
    if (hl == 0) wsTheta[2 * w + half] = cs;
}

// Kernel B: oriented pooling + gating + output.
__global__ __launch_bounds__(256) void pool_kernel(
    const float* __restrict__ x,
    const float* __restrict__ br, const float* __restrict__ we,
    const float* __restrict__ be, const f2* __restrict__ ws,
    const f2* __restrict__ wsTheta,
    float* __restrict__ out) {
    const int lane = threadIdx.x & 63;
    const int hl = lane & 31;
    const int half = lane >> 5;
    const int w = __builtin_amdgcn_readfirstlane(blockIdx.x * 4 + (threadIdx.x >> 6));
    const int b   = w >> 15;
    const int yq  = (w >> 7) & 255;
    const int xq0 = (2 * w) & 255;
    const int xql = xq0 + half;
    const char* xb = (const char*)(x + ((size_t)b << 22));
    const unsigned laneoff = (unsigned)hl << 3;

    f2 cs = wsTheta[2 * w + half];
    const float ct = cs.x, st = cs.y;

    const float fy = (float)yq, fx = (float)xql;
    f2 at0 = sp(0.f), at1 = sp(0.f), an0 = sp(0.f), an1 = sp(0.f);
#pragma unroll
    for (int t = -4; t <= 4; ++t) {
        float tf = (float)t;
        bilin2(xb, laneoff, fmaf(tf, st, fy), fmaf(tf, ct, fx), (t & 1) ? at1 : at0);
        bilin2(xb, laneoff, fmaf(tf, ct, fy), fmaf(-tf, st, fx), (t & 1) ? an1 : an0);
    }
    f2 tan2; tan2.x = (at0.x + at1.x) * (1.f / 9.f); tan2.y = (at0.y + at1.y) * (1.f / 9.f);
    f2 nor2; nor2.x = (an0.x + an1.x) * (1.f / 9.f); nor2.y = (an0.y + an1.y) * (1.f / 9.f);

    // ---- r = relu(wr . [tan;nor] + br) ----
    const int j = hl & 7;
    const f2* wrp = ws + 2304 + (hl << 3);
    const f2* wrn = ws + 2560 + (hl << 3);
    f2 p0 = pkfma(tan2, wrp[0], sp(0.f)); p0 = pkfma(nor2, wrn[0], p0);
    f2 p1 = pkfma(tan2, wrp[1], sp(0.f)); p1 = pkfma(nor2, wrn[1], p1);
    f2 p2 = pkfma(tan2, wrp[2], sp(0.f)); p2 = pkfma(nor2, wrn[2], p2);
    f2 p3 = pkfma(tan2, wrp[3], sp(0.f)); p3 = pkfma(nor2, wrn[3], p3);
    f2 p4 = pkfma(tan2, wrp[4], sp(0.f)); p4 = pkfma(nor2, wrn[4], p4);
    f2 p5 = pkfma(tan2, wrp[5], sp(0.f)); p5 = pkfma(nor2, wrn[5], p5);
    f2 p6 = pkfma(tan2, wrp[6], sp(0.f)); p6 = pkfma(nor2, wrn[6], p6);
    f2 p7 = pkfma(tan2, wrp[7], sp(0.f)); p7 = pkfma(nor2, wrn[7], p7);
    float rsum = fold8h(p0.x + p0.y, p1.x + p1.y, p2.x + p2.y, p3.x + p3.y,
                        p4.x + p4.y, p5.x + p5.y, p6.x + p6.y, p7.x + p7.y, hl);
    float r_l = fmaxf(rsum + br[j], 0.f);   // lane holds r[j], j = hl&7

    // broadcast within half: slot m holds r[j ^ m]
    float rb0 = r_l;
    float rb1 = __shfl_xor(rb0, 1, 64);
    float rb2 = __shfl_xor(rb0, 2, 64);
    float rb3 = __shfl_xor(rb1, 2, 64);
    float rb4 = __shfl_xor(rb0, 4, 64);
    float rb5 = __shfl_xor(rb1, 4, 64);
    float rb6 = __shfl_xor(rb2, 4, 64);
    float rb7 = __shfl_xor(rb3, 4, 64);

    // ---- w = sigmoid(we . r + be), packed channel pairs ----
    const char* web = (const char*)we;
    unsigned voff = ((unsigned)j << 9) | laneoff;
    f2 zt2 = *(const f2*)((const char*)be + laneoff);
    f2 zn2 = *(const f2*)((const char*)be + 256 + laneoff);
#pragma unroll
    for (int m = 0; m < 8; ++m) {
        unsigned vm = voff ^ ((unsigned)m << 9);
        float rbm = (m == 0) ? rb0 : (m == 1) ? rb1 : (m == 2) ? rb2 : (m == 3) ? rb3
                  : (m == 4) ? rb4 : (m == 5) ? rb5 : (m == 6) ? rb6 : rb7;
        zt2 = pkfma(sp(rbm), *(const f2*)(web + vm), zt2);
        zn2 = pkfma(sp(rbm), *(const f2*)(web + vm + 256), zn2);
    }
    f2 wt2, wn2;
    wt2.x = __builtin_amdgcn_rcpf(1.f + __expf(-zt2.x));
    wt2.y = __builtin_amdgcn_rcpf(1.f + __expf(-zt2.y));
    wn2.x = __builtin_amdgcn_rcpf(1.f + __expf(-zn2.x));
    wn2.y = __builtin_amdgcn_rcpf(1.f + __expf(-zn2.y));

    f2 xc2 = *(const f2*)(xb + (((unsigned)yq << 16) + ((unsigned)xql << 8) + laneoff));
    f2 o; o.x = (wt2.x + wn2.x) * xc2.x; o.y = (wt2.y + wn2.y) * xc2.y;
    *(f2*)((char*)out + (((size_t)w) << 9) + ((unsigned)lane << 3)) = o;
}

extern "C" void kernel_launch(void* const* d_in, const int* in_sizes, int n_in,
                              void* d_out, int out_size, void* d_ws, size_t ws_size,
                              hipStream_t stream) {
    const float* x  = (const float*)d_in[0];
    const float* w3 = (const float*)d_in[1];
    const float* b3 = (const float*)d_in[2];
    const float* w1 = (const float*)d_in[3];
    const float* b1 = (const float*)d_in[4];
    const float* wr = (const float*)d_in[5];
    const float* br = (const float*)d_in[6];
    const float* we = (const float*)d_in[7];
    const float* be = (const float*)d_in[8];
    float* out = (float*)d_out;
    f2* ws = (f2*)d_ws;
    f2* wsTheta = ws + 4096;   // 512K f2 = 4 MB for per-pixel {cos, sin}

    repack_kernel<<<11, 256, 0, stream>>>(w3, wr, ws);

    const int total_waves = Bq * Hq * Wq / 2;   // one wave per pixel PAIR
    dim3 grid(total_waves / 4), block(256);
    theta_kernel<<<grid, block, 0, stream>>>(x, b3, w1, b1, ws, wsTheta);
    pool_kernel<<<grid, block, 0, stream>>>(x, br, we, be, ws, wsTheta, out);
}

// Round 8
// 1341.717 us; speedup vs baseline: 2.2891x; 1.0144x over previous
//
#include <hip/hip_runtime.h>
#include <math.h>

#define Bq 8
#define Hq 256
#define Wq 256
#define Cq 64
#define HID 8
#define PI_F 3.14159265358979323846f

typedef float f2 __attribute__((ext_vector_type(2)));

__device__ __forceinline__ f2 pkfma(f2 a, f2 b, f2 c) {
#if __has_builtin(__builtin_elementwise_fma)
    return __builtin_elementwise_fma(a, b, c);
#else
    f2 r; r.x = fmaf(a.x, b.x, c.x); r.y = fmaf(a.y, b.y, c.y); return r;
#endif
}
__device__ __forceinline__ f2 sp(float v) { f2 r; r.x = v; r.y = v; return r; }

// Sum v[hl&7] over the lane's OWN 32-lane half (two pixels per wave).
__device__ __forceinline__ float fold8h(float v0, float v1, float v2, float v3,
                                        float v4, float v5, float v6, float v7,
                                        int hl) {
    const bool b4 = (hl & 4) != 0;
    float k0 = b4 ? v4 : v0, g0 = b4 ? v0 : v4;
    float k1 = b4 ? v5 : v1, g1 = b4 ? v1 : v5;
    float k2 = b4 ? v6 : v2, g2 = b4 ? v2 : v6;
    float k3 = b4 ? v7 : v3, g3 = b4 ? v3 : v7;
    k0 += __shfl_xor(g0, 4, 64);
    k1 += __shfl_xor(g1, 4, 64);
    k2 += __shfl_xor(g2, 4, 64);
    k3 += __shfl_xor(g3, 4, 64);
    const bool b2 = (hl & 2) != 0;
    float m0 = b2 ? k2 : k0, n0 = b2 ? k0 : k2;
    float m1 = b2 ? k3 : k1, n1 = b2 ? k1 : k3;
    m0 += __shfl_xor(n0, 2, 64);
    m1 += __shfl_xor(n1, 2, 64);
    const bool b1_ = (hl & 1) != 0;
    float q = b1_ ? m1 : m0, r = b1_ ? m0 : m1;
    q += __shfl_xor(r, 1, 64);
    q += __shfl_xor(q, 8, 64);
    q += __shfl_xor(q, 16, 64);
    return q;
}

// ---- bilinear sample, split into prep / load / accumulate so that many
// loads can be issued back-to-back before any consumer FMA (ILP) ----
struct S4 { unsigned a0, a1, a2, a3; float w00, w01, w10, w11; };
struct L4 { f2 I0, I1, I2, I3; };

__device__ __forceinline__ S4 prep(float cy, float cx, unsigned laneoff) {
    float fy0 = floorf(cy), fx0 = floorf(cx);
    int y0 = (int)fy0, x0 = (int)fx0;
    int y0i = min(max(y0, 0), Hq - 1);
    int y1i = min(max(y0 + 1, 0), Hq - 1);
    int x0i = min(max(x0, 0), Wq - 1);
    int x1i = min(max(x0 + 1, 0), Wq - 1);
    float wy0 = (float)y1i - cy, wy1 = cy - (float)y0i;
    float wx0 = (float)x1i - cx, wx1 = cx - (float)x0i;
    unsigned r0 = ((unsigned)y0i << 16) + laneoff;
    unsigned r1 = ((unsigned)y1i << 16) + laneoff;
    unsigned c0 = (unsigned)x0i << 8, c1 = (unsigned)x1i << 8;
    S4 s;
    s.a0 = r0 + c0; s.a1 = r1 + c0; s.a2 = r0 + c1; s.a3 = r1 + c1;
    s.w00 = wx0 * wy0; s.w01 = wx0 * wy1; s.w10 = wx1 * wy0; s.w11 = wx1 * wy1;
    return s;
}
__device__ __forceinline__ L4 ld4(const char* __restrict__ xb, const S4& s) {
    L4 l;
    l.I0 = *(const f2*)(xb + s.a0);
    l.I1 = *(const f2*)(xb + s.a1);
    l.I2 = *(const f2*)(xb + s.a2);
    l.I3 = *(const f2*)(xb + s.a3);
    return l;
}
__device__ __forceinline__ void acc4(const S4& s, const L4& l, f2& acc) {
    acc = pkfma(sp(s.w00), l.I0, acc);
    acc = pkfma(sp(s.w01), l.I1, acc);
    acc = pkfma(sp(s.w10), l.I2, acc);
    acc = pkfma(sp(s.w11), l.I3, acc);
}

// Repack w3 [9][64][8] -> ws[tap][hl][j] = {w3[tap][2hl][j], w3[tap][2hl+1][j]}
// and wr [128][8] -> pairs. 2816 f2 elements.
__global__ void repack_kernel(const float* __restrict__ w3,
                              const float* __restrict__ wr,
                              f2* __restrict__ ws) {
    int t = blockIdx.x * 256 + threadIdx.x;
    if (t < 2304) {
        int tap = t >> 8, rem = t & 255, hl = rem >> 3, j = rem & 7;
        f2 v; v.x = w3[((tap << 6) + (hl << 1)) * 8 + j];
        v.y = w3[((tap << 6) + (hl << 1) + 1) * 8 + j];
        ws[t] = v;
    } else if (t < 2560) {
        int rem = t - 2304, hl = rem >> 3, j = rem & 7;
        f2 v; v.x = wr[(hl << 1) * 8 + j];
        v.y = wr[((hl << 1) + 1) * 8 + j];
        ws[t] = v;
    } else if (t < 2816) {
        int rem = t - 2560, hl = rem >> 3, j = rem & 7;
        f2 v; v.x = wr[(64 + (hl << 1)) * 8 + j];
        v.y = wr[(64 + (hl << 1) + 1) * 8 + j];
        ws[t] = v;
    }
}

// Kernel A: conv3x3 -> h -> theta -> {cos, sin} per pixel into wsTheta.
// All 9 tap loads issued as a clump before the FMA block (latency hiding).
#define TAPADDR(I, DY, DX) \
    int yy##I = yq + (DY); int xx##I = xql + (DX); \
    bool v##I = ((unsigned)yy##I < (unsigned)Hq) && ((unsigned)xx##I < (unsigned)Wq); \
    unsigned ad##I = (((unsigned)min(max(yy##I, 0), Hq - 1)) << 16) \
                   + (((unsigned)min(max(xx##I, 0), Wq - 1)) << 8) + laneoff;
#define TAPLOAD(I) f2 xv##I = *(const f2*)(xb + ad##I);
#define TAPMASK(I) xv##I = v##I ? xv##I : sp(0.f);
#define TAPFMA(I) { const f2* wp = ws + ((I) << 8) + (hl << 3); \
    a0 = pkfma(xv##I, wp[0], a0); a1 = pkfma(xv##I, wp[1], a1); \
    a2 = pkfma(xv##I, wp[2], a2); a3 = pkfma(xv##I, wp[3], a3); \
    a4 = pkfma(xv##I, wp[4], a4); a5 = pkfma(xv##I, wp[5], a5); \
    a6 = pkfma(xv##I, wp[6], a6); a7 = pkfma(xv##I, wp[7], a7); }

__global__ __launch_bounds__(256) void theta_kernel(
    const float* __restrict__ x,
    const float* __restrict__ b3, const float* __restrict__ w1,
    const float* __restrict__ b1, const f2* __restrict__ ws,
    f2* __restrict__ wsTheta) {
    const int lane = threadIdx.x & 63;
    const int hl = lane & 31;
    const int half = lane >> 5;
    const int w = __builtin_amdgcn_readfirstlane(blockIdx.x * 4 + (threadIdx.x >> 6));
    const int b   = w >> 15;
    const int yq  = (w >> 7) & 255;
    const int xq0 = (2 * w) & 255;
    const int xql = xq0 + half;
    const char* xb = (const char*)(x + ((size_t)b << 22));
    const unsigned laneoff = (unsigned)hl << 3;

    TAPADDR(0, -1, -1) TAPADDR(1, -1, 0) TAPADDR(2, -1, 1)
    TAPADDR(3,  0, -1) TAPADDR(4,  0, 0) TAPADDR(5,  0, 1)
    TAPADDR(6,  1, -1) TAPADDR(7,  1, 0) TAPADDR(8,  1, 1)
    TAPLOAD(0) TAPLOAD(1) TAPLOAD(2) TAPLOAD(3) TAPLOAD(4)
    TAPLOAD(5) TAPLOAD(6) TAPLOAD(7) TAPLOAD(8)
    TAPMASK(0) TAPMASK(1) TAPMASK(2) TAPMASK(3) TAPMASK(4)
    TAPMASK(5) TAPMASK(6) TAPMASK(7) TAPMASK(8)

    f2 a0 = sp(0.f), a1 = sp(0.f), a2 = sp(0.f), a3 = sp(0.f);
    f2 a4 = sp(0.f), a5 = sp(0.f), a6 = sp(0.f), a7 = sp(0.f);
    TAPFMA(0) TAPFMA(1) TAPFMA(2) TAPFMA(3) TAPFMA(4)
    TAPFMA(5) TAPFMA(6) TAPFMA(7) TAPFMA(8)

    const int j = hl & 7;
    float hsum = fold8h(a0.x + a0.y, a1.x + a1.y, a2.x + a2.y, a3.x + a3.y,
                        a4.x + a4.y, a5.x + a5.y, a6.x + a6.y, a7.x + a7.y, hl);
    float h_l = fmaxf(hsum + b3[j], 0.f);

    float zp = h_l * w1[j];
    zp += __shfl_xor(zp, 1, 64);
    zp += __shfl_xor(zp, 2, 64);
    zp += __shfl_xor(zp, 4, 64);
    float z = zp + b1[0];
    float theta = PI_F * __builtin_amdgcn_rcpf(1.f + __expf(-z));
    f2 cs; cs.x = __cosf(theta); cs.y = __sinf(theta);
    if (hl == 0) wsTheta[2 * w + half] = cs;
}

// Kernel B: oriented pooling + gating. The 9 (t) x 2 (dir) samples are
// processed in 3 groups of 3 t-steps; each group issues all 24 corner
// loads before any FMA consumes them (deep in-flight VMEM).
__global__ __launch_bounds__(256) void pool_kernel(
    const float* __restrict__ x,
    const float* __restrict__ br, const float* __restrict__ we,
    const float* __restrict__ be, const f2* __restrict__ ws,
    const f2* __restrict__ wsTheta,
    float* __restrict__ out) {
    const int lane = threadIdx.x & 63;
    const int hl = lane & 31;
    const int half = lane >> 5;
    const int w = __builtin_amdgcn_readfirstlane(blockIdx.x * 4 + (threadIdx.x >> 6));
    const int b   = w >> 15;
    const int yq  = (w >> 7) & 255;
    const int xq0 = (2 * w) & 255;
    const int xql = xq0 + half;
    const char* xb = (const char*)(x + ((size_t)b << 22));
    const unsigned laneoff = (unsigned)hl << 3;

    f2 cs = wsTheta[2 * w + half];
    const float vcos = cs.x, vsin = cs.y;

    const float fy = (float)yq, fx = (float)xql;
    f2 at0 = sp(0.f), at1 = sp(0.f), an0 = sp(0.f), an1 = sp(0.f);
#pragma unroll
    for (int g = 0; g < 3; ++g) {
        const float t0f = (float)(3 * g - 4);
        const float t1f = t0f + 1.f;
        const float t2f = t0f + 2.f;
        // prep: addresses + weights for 6 samples (3 t-steps x 2 directions)
        S4 sT0 = prep(fmaf(t0f, vsin, fy), fmaf(t0f, vcos, fx), laneoff);
        S4 sN0 = prep(fmaf(t0f, vcos, fy), fmaf(-t0f, vsin, fx), laneoff);
        S4 sT1 = prep(fmaf(t1f, vsin, fy), fmaf(t1f, vcos, fx), laneoff);
        S4 sN1 = prep(fmaf(t1f, vcos, fy), fmaf(-t1f, vsin, fx), laneoff);
        S4 sT2 = prep(fmaf(t2f, vsin, fy), fmaf(t2f, vcos, fx), laneoff);
        S4 sN2 = prep(fmaf(t2f, vcos, fy), fmaf(-t2f, vsin, fx), laneoff);
        // load clump: 24 independent 8B loads in flight
        L4 lT0 = ld4(xb, sT0);
        L4 lN0 = ld4(xb, sN0);
        L4 lT1 = ld4(xb, sT1);
        L4 lN1 = ld4(xb, sN1);
        L4 lT2 = ld4(xb, sT2);
        L4 lN2 = ld4(xb, sN2);
        // consume
        acc4(sT0, lT0, at0);
        acc4(sN0, lN0, an0);
        acc4(sT1, lT1, at1);
        acc4(sN1, lN1, an1);
        acc4(sT2, lT2, at0);
        acc4(sN2, lN2, an0);
    }
    f2 tan2; tan2.x = (at0.x + at1.x) * (1.f / 9.f); tan2.y = (at0.y + at1.y) * (1.f / 9.f);
    f2 nor2; nor2.x = (an0.x + an1.x) * (1.f / 9.f); nor2.y = (an0.y + an1.y) * (1.f / 9.f);

    // ---- r = relu(wr . [tan;nor] + br) ----
    const int j = hl & 7;
    const f2* wrp = ws + 2304 + (hl << 3);
    const f2* wrn = ws + 2560 + (hl << 3);
    f2 p0 = pkfma(tan2, wrp[0], sp(0.f)); p0 = pkfma(nor2, wrn[0], p0);
    f2 p1 = pkfma(tan2, wrp[1], sp(0.f)); p1 = pkfma(nor2, wrn[1], p1);
    f2 p2 = pkfma(tan2, wrp[2], sp(0.f)); p2 = pkfma(nor2, wrn[2], p2);
    f2 p3 = pkfma(tan2, wrp[3], sp(0.f)); p3 = pkfma(nor2, wrn[3], p3);
    f2 p4 = pkfma(tan2, wrp[4], sp(0.f)); p4 = pkfma(nor2, wrn[4], p4);
    f2 p5 = pkfma(tan2, wrp[5], sp(0.f)); p5 = pkfma(nor2, wrn[5], p5);
    f2 p6 = pkfma(tan2, wrp[6], sp(0.f)); p6 = pkfma(nor2, wrn[6], p6);
    f2 p7 = pkfma(tan2, wrp[7], sp(0.f)); p7 = pkfma(nor2, wrn[7], p7);
    float rsum = fold8h(p0.x + p0.y, p1.x + p1.y, p2.x + p2.y, p3.x + p3.y,
                        p4.x + p4.y, p5.x + p5.y, p6.x + p6.y, p7.x + p7.y, hl);
    float r_l = fmaxf(rsum + br[j], 0.f);   // lane holds r[j], j = hl&7

    // broadcast within half: slot m holds r[j ^ m]
    float rb0 = r_l;
    float rb1 = __shfl_xor(rb0, 1, 64);
    float rb2 = __shfl_xor(rb0, 2, 64);
    float rb3 = __shfl_xor(rb1, 2, 64);
    float rb4 = __shfl_xor(rb0, 4, 64);
    float rb5 = __shfl_xor(rb1, 4, 64);
    float rb6 = __shfl_xor(rb2, 4, 64);
    float rb7 = __shfl_xor(rb3, 4, 64);

    // ---- w = sigmoid(we . r + be), packed channel pairs ----
    const char* web = (const char*)we;
    unsigned voff = ((unsigned)j << 9) | laneoff;
    f2 zt2 = *(const f2*)((const char*)be + laneoff);
    f2 zn2 = *(const f2*)((const char*)be + 256 + laneoff);
#pragma unroll
    for (int m = 0; m < 8; ++m) {
        unsigned vm = voff ^ ((unsigned)m << 9);
        float rbm = (m == 0) ? rb0 : (m == 1) ? rb1 : (m == 2) ? rb2 : (m == 3) ? rb3
                  : (m == 4) ? rb4 : (m == 5) ? rb5 : (m == 6) ? rb6 : rb7;
        zt2 = pkfma(sp(rbm), *(const f2*)(web + vm), zt2);
        zn2 = pkfma(sp(rbm), *(const f2*)(web + vm + 256), zn2);
    }
    f2 wt2, wn2;
    wt2.x = __builtin_amdgcn_rcpf(1.f + __expf(-zt2.x));
    wt2.y = __builtin_amdgcn_rcpf(1.f + __expf(-zt2.y));
    wn2.x = __builtin_amdgcn_rcpf(1.f + __expf(-zn2.x));
    wn2.y = __builtin_amdgcn_rcpf(1.f + __expf(-zn2.y));

    f2 xc2 = *(const f2*)(xb + (((unsigned)yq << 16) + ((unsigned)xql << 8) + laneoff));
    f2 o; o.x = (wt2.x + wn2.x) * xc2.x; o.y = (wt2.y + wn2.y) * xc2.y;
    *(f2*)((char*)out + (((size_t)w) << 9) + ((unsigned)lane << 3)) = o;
}

extern "C" void kernel_launch(void* const* d_in, const int* in_sizes, int n_in,
                              void* d_out, int out_size, void* d_ws, size_t ws_size,
                              hipStream_t stream) {
    const float* x  = (const float*)d_in[0];
    const float* w3 = (const float*)d_in[1];
    const float* b3 = (const float*)d_in[2];
    const float* w1 = (const float*)d_in[3];
    const float* b1 = (const float*)d_in[4];
    const float* wr = (const float*)d_in[5];
    const float* br = (const float*)d_in[6];
    const float* we = (const float*)d_in[7];
    const float* be = (const float*)d_in[8];
    float* out = (float*)d_out;
    f2* ws = (f2*)d_ws;
    f2* wsTheta = ws + 4096;   // 512K f2 = 4 MB for per-pixel {cos, sin}

    repack_kernel<<<11, 256, 0, stream>>>(w3, wr, ws);

    const int total_waves = Bq * Hq * Wq / 2;   // one wave per pixel PAIR
    dim3 grid(total_waves / 4), block(256);
    theta_kernel<<<grid, block, 0, stream>>>(x, b3, w1, b1, ws, wsTheta);
    pool_kernel<<<grid, block, 0, stream>>>(x, br, we, be, ws, wsTheta, out);
}

// Round 9
// 1069.148 us; speedup vs baseline: 2.8727x; 1.2549x over previous
//
#include <hip/hip_runtime.h>
#include <math.h>

#define PI_F 3.14159265358979323846f

typedef float f2 __attribute__((ext_vector_type(2)));

__device__ __forceinline__ f2 pkfma(f2 a, f2 b, f2 c) {
    return __builtin_elementwise_fma(a, b, c);
}
__device__ __forceinline__ f2 sp(float v) { f2 r; r.x = v; r.y = v; return r; }
__device__ __forceinline__ f2 mk2(float a, float b) { f2 r; r.x = a; r.y = b; return r; }

// Sum v[hl&7] over the lane's OWN 32-lane half (two pixels per wave).
__device__ __forceinline__ float fold8h(float v0, float v1, float v2, float v3,
                                        float v4, float v5, float v6, float v7,
                                        int hl) {
    const bool b4 = (hl & 4) != 0;
    float k0 = b4 ? v4 : v0, g0 = b4 ? v0 : v4;
    float k1 = b4 ? v5 : v1, g1 = b4 ? v1 : v5;
    float k2 = b4 ? v6 : v2, g2 = b4 ? v2 : v6;
    float k3 = b4 ? v7 : v3, g3 = b4 ? v3 : v7;
    k0 += __shfl_xor(g0, 4, 64);
    k1 += __shfl_xor(g1, 4, 64);
    k2 += __shfl_xor(g2, 4, 64);
    k3 += __shfl_xor(g3, 4, 64);
    const bool b2 = (hl & 2) != 0;
    float m0 = b2 ? k2 : k0, n0 = b2 ? k0 : k2;
    float m1 = b2 ? k3 : k1, n1 = b2 ? k1 : k3;
    m0 += __shfl_xor(n0, 2, 64);
    m1 += __shfl_xor(n1, 2, 64);
    const bool b1_ = (hl & 1) != 0;
    float q = b1_ ? m1 : m0, r = b1_ ? m0 : m1;
    q += __shfl_xor(r, 1, 64);
    q += __shfl_xor(q, 8, 64);
    q += __shfl_xor(q, 16, 64);
    return q;
}

// Repack w3 [9][64][8] -> ws[tap][hl][j] (channel-pair f2) and wr [128][8]
// -> tan/nor pair tables. 2816 f2 elements.
__global__ void repack_kernel(const float* __restrict__ w3,
                              const float* __restrict__ wr,
                              f2* __restrict__ ws) {
    int t = blockIdx.x * 256 + threadIdx.x;
    if (t < 2304) {
        int tap = t >> 8, rem = t & 255, hl = rem >> 3, j = rem & 7;
        f2 v; v.x = w3[((tap << 6) + (hl << 1)) * 8 + j];
        v.y = w3[((tap << 6) + (hl << 1) + 1) * 8 + j];
        ws[t] = v;
    } else if (t < 2560) {
        int rem = t - 2304, hl = rem >> 3, j = rem & 7;
        f2 v; v.x = wr[(hl << 1) * 8 + j];
        v.y = wr[((hl << 1) + 1) * 8 + j];
        ws[t] = v;
    } else if (t < 2816) {
        int rem = t - 2560, hl = rem >> 3, j = rem & 7;
        f2 v; v.x = wr[(64 + (hl << 1)) * 8 + j];
        v.y = wr[(64 + (hl << 1) + 1) * 8 + j];
        ws[t] = v;
    }
}

// LDS tile: 11 rows x 17 cols x 64 ch (fp32) = 47872 B.
#define TR 11
#define TC 17

// Bilinear sample from the LDS tile. Weights from CLIPPED integer global
// corner coords (faithful to reference); addresses are tile-relative.
__device__ __forceinline__ f2 bilin_lds(const char* tb, float cy, float cx,
                                        int ybase, int xbase, unsigned laneoff,
                                        f2 acc) {
    int y0 = (int)floorf(cy), x0 = (int)floorf(cx);
    int y0i = min(max(y0, 0), 255);
    int y1i = min(max(y0 + 1, 0), 255);
    int x0i = min(max(x0, 0), 255);
    int x1i = min(max(x0 + 1, 0), 255);
    float wy0 = (float)y1i - cy, wy1 = cy - (float)y0i;
    float wx0 = (float)x1i - cx, wx1 = cx - (float)x0i;
    unsigned r0 = (unsigned)((y0i - ybase) * TC) << 8;
    unsigned r1 = (unsigned)((y1i - ybase) * TC) << 8;
    unsigned c0 = ((unsigned)(x0i - xbase) << 8) + laneoff;
    unsigned c1 = ((unsigned)(x1i - xbase) << 8) + laneoff;
    f2 Ia = *(const f2*)(tb + (r0 + c0));
    f2 Ib = *(const f2*)(tb + (r1 + c0));
    f2 Ic = *(const f2*)(tb + (r0 + c1));
    f2 Id = *(const f2*)(tb + (r1 + c1));
    acc = pkfma(sp(wx0 * wy0), Ia, acc);
    acc = pkfma(sp(wx0 * wy1), Ib, acc);
    acc = pkfma(sp(wx1 * wy0), Ic, acc);
    acc = pkfma(sp(wx1 * wy1), Id, acc);
    return acc;
}

// Fused kernel: one block = 16 pixels (2 rows x 8 cols), 8 waves, one
// pixel PAIR per wave (lanes 0-31 pixel A, 32-63 pixel B, lane = ch pair).
// Stages the shared 11x17 pixel neighborhood into LDS once, then does
// conv3x3 -> theta -> 18 bilinear samples -> gating entirely from LDS.
__global__ __launch_bounds__(512) void oca_kernel(
    const float* __restrict__ x,
    const float* __restrict__ b3, const float* __restrict__ w1,
    const float* __restrict__ b1, const float* __restrict__ br,
    const float* __restrict__ we, const float* __restrict__ be,
    const f2* __restrict__ ws,
    float* __restrict__ out) {
    __shared__ float tile[TR * TC * 64];
    const int tid = threadIdx.x;
    const int lane = tid & 63;
    const int hl = lane & 31;
    const int half = lane >> 5;
    const int wid = __builtin_amdgcn_readfirstlane(tid >> 6);   // 0..7

    const unsigned beta = blockIdx.x;
    const int b   = beta >> 12;            // 128*32 tiles per batch
    const int ty  = (beta >> 5) & 127;
    const int tx  = beta & 31;
    const int yq0 = ty << 1;
    const int xq0 = tx << 3;
    const int ybase = yq0 - 4;
    const int xbase = xq0 - 4;
    const float* xb = x + ((size_t)b << 22);

    // ---- stage 187 pixels x 256 B: 16-thread groups, float4 each ----
    {
        const int g   = tid >> 4;          // 0..31
        const int sub = (tid & 15) << 2;   // float offset within pixel
        for (int p = g; p < TR * TC; p += 32) {
            int pr = p / TC;
            int pc = p - pr * TC;
            int gy = min(max(ybase + pr, 0), 255);
            int gx = min(max(xbase + pc, 0), 255);
            float4 v = *(const float4*)(xb + (size_t)(((gy << 8) + gx) << 6) + sub);
            *(float4*)((char*)tile + (p << 8) + (sub << 2)) = v;
        }
    }
    __syncthreads();

    const int yqw = yq0 + (wid >> 2);                 // this wave's row
    const int xql = xq0 + ((wid & 3) << 1) + half;    // this lane's pixel col
    const unsigned laneoff = (unsigned)hl << 3;
    const char* tb = (const char*)tile;

    // ---- conv3x3 -> 8 hidden partials (zero-padded borders) ----
    f2 a0 = sp(0.f), a1 = sp(0.f), a2 = sp(0.f), a3 = sp(0.f);
    f2 a4 = sp(0.f), a5 = sp(0.f), a6 = sp(0.f), a7 = sp(0.f);
    f2 xc2 = sp(0.f);
#pragma unroll
    for (int dy = -1; dy <= 1; ++dy) {
#pragma unroll
        for (int dx = -1; dx <= 1; ++dx) {
            int yy = yqw + dy;
            int xx = xql + dx;
            bool valid = ((unsigned)yy < 256u) && ((unsigned)xx < 256u);
            int ry = min(max(yy, 0), 255) - ybase;
            int cx = min(max(xx, 0), 255) - xbase;
            f2 xv = *(const f2*)(tb + (((unsigned)(ry * TC + cx) << 8) + laneoff));
            xv = valid ? xv : sp(0.f);
            if (dy == 0 && dx == 0) xc2 = xv;
            const int tap = (dy + 1) * 3 + (dx + 1);
            const float4* wq = (const float4*)(ws + (tap << 8) + (hl << 3));
            float4 q0 = wq[0], q1 = wq[1], q2 = wq[2], q3 = wq[3];
            a0 = pkfma(xv, mk2(q0.x, q0.y), a0);
            a1 = pkfma(xv, mk2(q0.z, q0.w), a1);
            a2 = pkfma(xv, mk2(q1.x, q1.y), a2);
            a3 = pkfma(xv, mk2(q1.z, q1.w), a3);
            a4 = pkfma(xv, mk2(q2.x, q2.y), a4);
            a5 = pkfma(xv, mk2(q2.z, q2.w), a5);
            a6 = pkfma(xv, mk2(q3.x, q3.y), a6);
            a7 = pkfma(xv, mk2(q3.z, q3.w), a7);
        }
    }
    const int j = hl & 7;
    float hsum = fold8h(a0.x + a0.y, a1.x + a1.y, a2.x + a2.y, a3.x + a3.y,
                        a4.x + a4.y, a5.x + a5.y, a6.x + a6.y, a7.x + a7.y, hl);
    float h_l = fmaxf(hsum + b3[j], 0.f);

    // ---- theta (per half-wave) ----
    float zp = h_l * w1[j];
    zp += __shfl_xor(zp, 1, 64);
    zp += __shfl_xor(zp, 2, 64);
    zp += __shfl_xor(zp, 4, 64);
    float z = zp + b1[0];
    float theta = PI_F * __builtin_amdgcn_rcpf(1.f + __expf(-z));
    float vcos = __cosf(theta);
    float vsin = __sinf(theta);

    // ---- oriented pooling from LDS ----
    const float fy = (float)yqw, fx = (float)xql;
    f2 at0 = sp(0.f), at1 = sp(0.f), an0 = sp(0.f), an1 = sp(0.f);
#pragma unroll
    for (int t = -4; t <= 4; ++t) {
        float tf = (float)t;
        f2& accT = (t & 1) ? at1 : at0;
        f2& accN = (t & 1) ? an1 : an0;
        accT = bilin_lds(tb, fmaf(tf, vsin, fy), fmaf(tf, vcos, fx),
                         ybase, xbase, laneoff, accT);
        accN = bilin_lds(tb, fmaf(tf, vcos, fy), fmaf(-tf, vsin, fx),
                         ybase, xbase, laneoff, accN);
    }
    f2 tan2 = mk2((at0.x + at1.x) * (1.f / 9.f), (at0.y + at1.y) * (1.f / 9.f));
    f2 nor2 = mk2((an0.x + an1.x) * (1.f / 9.f), (an0.y + an1.y) * (1.f / 9.f));

    // ---- r = relu(wr . [tan;nor] + br) ----
    const f2* wrp = ws + 2304 + (hl << 3);
    const f2* wrn = ws + 2560 + (hl << 3);
    f2 p0 = pkfma(tan2, wrp[0], sp(0.f)); p0 = pkfma(nor2, wrn[0], p0);
    f2 p1 = pkfma(tan2, wrp[1], sp(0.f)); p1 = pkfma(nor2, wrn[1], p1);
    f2 p2 = pkfma(tan2, wrp[2], sp(0.f)); p2 = pkfma(nor2, wrn[2], p2);
    f2 p3 = pkfma(tan2, wrp[3], sp(0.f)); p3 = pkfma(nor2, wrn[3], p3);
    f2 p4 = pkfma(tan2, wrp[4], sp(0.f)); p4 = pkfma(nor2, wrn[4], p4);
    f2 p5 = pkfma(tan2, wrp[5], sp(0.f)); p5 = pkfma(nor2, wrn[5], p5);
    f2 p6 = pkfma(tan2, wrp[6], sp(0.f)); p6 = pkfma(nor2, wrn[6], p6);
    f2 p7 = pkfma(tan2, wrp[7], sp(0.f)); p7 = pkfma(nor2, wrn[7], p7);
    float rsum = fold8h(p0.x + p0.y, p1.x + p1.y, p2.x + p2.y, p3.x + p3.y,
                        p4.x + p4.y, p5.x + p5.y, p6.x + p6.y, p7.x + p7.y, hl);
    float r_l = fmaxf(rsum + br[j], 0.f);   // lane holds r[j], j = hl&7

    // broadcast within half: slot m holds r[j ^ m]
    float rb0 = r_l;
    float rb1 = __shfl_xor(rb0, 1, 64);
    float rb2 = __shfl_xor(rb0, 2, 64);
    float rb3 = __shfl_xor(rb1, 2, 64);
    float rb4 = __shfl_xor(rb0, 4, 64);
    float rb5 = __shfl_xor(rb1, 4, 64);
    float rb6 = __shfl_xor(rb2, 4, 64);
    float rb7 = __shfl_xor(rb3, 4, 64);

    // ---- w = sigmoid(we . r + be), packed channel pairs ----
    const char* web = (const char*)we;
    unsigned voff = ((unsigned)j << 9) | laneoff;
    f2 zt2 = *(const f2*)((const char*)be + laneoff);
    f2 zn2 = *(const f2*)((const char*)be + 256 + laneoff);
#pragma unroll
    for (int m = 0; m < 8; ++m) {
        unsigned vm = voff ^ ((unsigned)m << 9);
        float rbm = (m == 0) ? rb0 : (m == 1) ? rb1 : (m == 2) ? rb2 : (m == 3) ? rb3
                  : (m == 4) ? rb4 : (m == 5) ? rb5 : (m == 6) ? rb6 : rb7;
        zt2 = pkfma(sp(rbm), *(const f2*)(web + vm), zt2);
        zn2 = pkfma(sp(rbm), *(const f2*)(web + vm + 256), zn2);
    }
    f2 wt2, wn2;
    wt2.x = __builtin_amdgcn_rcpf(1.f + __expf(-zt2.x));
    wt2.y = __builtin_amdgcn_rcpf(1.f + __expf(-zt2.y));
    wn2.x = __builtin_amdgcn_rcpf(1.f + __expf(-zn2.x));
    wn2.y = __builtin_amdgcn_rcpf(1.f + __expf(-zn2.y));

    // out byte = (pixelA_index << 8) + (lane << 3); halves are adjacent pixels
    f2 o = mk2((wt2.x + wn2.x) * xc2.x, (wt2.y + wn2.y) * xc2.y);
    size_t pixA = ((size_t)b << 16) + ((size_t)yqw << 8) + (size_t)(xq0 + ((wid & 3) << 1));
    *(f2*)((char*)out + (pixA << 8) + ((unsigned)lane << 3)) = o;
}

extern "C" void kernel_launch(void* const* d_in, const int* in_sizes, int n_in,
                              void* d_out, int out_size, void* d_ws, size_t ws_size,
                              hipStream_t stream) {
    const float* x  = (const float*)d_in[0];
    const float* w3 = (const float*)d_in[1];
    const float* b3 = (const float*)d_in[2];
    const float* w1 = (const float*)d_in[3];
    const float* b1 = (const float*)d_in[4];
    const float* wr = (const float*)d_in[5];
    const float* br = (const float*)d_in[6];
    const float* we = (const float*)d_in[7];
    const float* be = (const float*)d_in[8];
    float* out = (float*)d_out;
    f2* ws = (f2*)d_ws;

    repack_kernel<<<11, 256, 0, stream>>>(w3, wr, ws);

    // 524288 pixels / 16 per block = 32768 blocks of 512 threads
    dim3 grid(32768), block(512);
    oca_kernel<<<grid, block, 0, stream>>>(x, b3, w1, b1, br, we, be, ws, out);
}